// Round 1
// baseline (7958.006 us; speedup 1.0000x reference)
//
#include <hip/hip_runtime.h>
#include <math.h>

typedef __bf16 bf16_t;
typedef bf16_t bf16x8 __attribute__((ext_vector_type(8)));
typedef bf16_t bf16x4 __attribute__((ext_vector_type(4)));
typedef float  f32x4  __attribute__((ext_vector_type(4)));

#define NB    32     // batch
#define NNODE 512    // nodes
#define NH    64     // hidden
#define NF    384    // NUM_MATS * CONCAT
#define FTR   256    // featT rows used (xh:0..127, t1:128..255)

static __device__ __forceinline__ f32x4 mfma16(bf16x8 a, bf16x8 b, f32x4 c){
  return __builtin_amdgcn_mfma_f32_16x16x32_bf16(a, b, c, 0, 0, 0);
}

// ---------------- setup kernels ----------------
__global__ __launch_bounds__(256) void k_convert_S(const float* __restrict__ S,
                                                   bf16_t* __restrict__ Sb){
  int i = blockIdx.x * 256 + threadIdx.x;          // 65536 threads, 4 elems each
  f32x4 v = *(const f32x4*)&S[(size_t)i * 4];
  bf16x4 o;
  #pragma unroll
  for (int q = 0; q < 4; ++q) o[q] = (bf16_t)v[q];
  *(bf16x4*)&Sb[(size_t)i * 4] = o;
}

__global__ __launch_bounds__(256) void k_transW(const float* __restrict__ W,
                                                bf16_t* __restrict__ Wt, int OD){
  int i = blockIdx.x * 256 + threadIdx.x;
  int total = 2 * NF * OD;
  if (i >= total) return;
  int l = i / (NF * OD), rem = i - l * (NF * OD);
  int o = rem / NF, f = rem - o * NF;
  Wt[i] = (bf16_t)W[(size_t)(l * NF + f) * OD + o];
}

// generic f32 64x64-tile transpose: src R x C (ld src_ld) -> dst C x R (ld dst_ld)
__global__ __launch_bounds__(256) void k_transpose_f32(const float* __restrict__ src,
                                                       float* __restrict__ dst,
                                                       int src_ld, int dst_ld,
                                                       long src_bs, long dst_bs){
  __shared__ float tile[64 * 65];
  const float* s = src + blockIdx.z * src_bs + (size_t)(blockIdx.x * 64) * src_ld + blockIdx.y * 64;
  float* d = dst + blockIdx.z * dst_bs + (size_t)(blockIdx.y * 64) * dst_ld + blockIdx.x * 64;
  for (int i = threadIdx.x; i < 4096; i += 256){
    int r = i >> 6, c = i & 63;
    tile[c * 65 + r] = s[(size_t)r * src_ld + c];
  }
  __syncthreads();
  for (int i = threadIdx.x; i < 4096; i += 256){
    int r = i >> 6, c = i & 63;
    d[(size_t)r * dst_ld + c] = tile[r * 65 + c];
  }
}

// ---------------- concat: build xh into featT rows 0..127 and featN cols 0..127 ----
__global__ __launch_bounds__(256) void k_concat(const float* __restrict__ x,
                                                const float* __restrict__ h_t,
                                                bf16_t* featT, bf16_t* featN){
  __shared__ bf16_t tile[64 * 67];
  const int b = blockIdx.y, m0 = blockIdx.x * 64;
  const int tid = threadIdx.x;
  const float* xs = x + (size_t)(b * NNODE + m0) * NH;
  // x tile: rows m(64) x cols j(64)
  #pragma unroll
  for (int s = 0; s < 4; ++s){
    int i = tid + s * 256;                 // 1024
    int r = i >> 4, c = (i & 15) * 4;
    f32x4 v = *(const f32x4*)&xs[(size_t)r * NH + c];
    bf16x4 bv;
    #pragma unroll
    for (int q = 0; q < 4; ++q) bv[q] = (bf16_t)v[q];
    *(bf16x4*)&featN[(size_t)(b * NNODE + m0 + r) * NF + c] = bv;
    #pragma unroll
    for (int q = 0; q < 4; ++q) tile[(c + q) * 67 + r] = bv[q];   // tile[j][m]
  }
  __syncthreads();
  #pragma unroll
  for (int s = 0; s < 2; ++s){
    int i = tid + s * 256;                 // 512: r=j(64) x 8-chunks of m
    int r = i >> 3, c = (i & 7) * 8;
    bf16x8 v;
    #pragma unroll
    for (int q = 0; q < 8; ++q) v[q] = tile[r * 67 + c + q];
    *(bf16x8*)&featT[(size_t)(b * FTR + r) * NNODE + m0 + c] = v;
  }
  __syncthreads();
  const float* hs = h_t + (size_t)(b * NH) * NNODE + m0;
  // h tile: rows o(64) x cols m(64)
  #pragma unroll
  for (int s = 0; s < 4; ++s){
    int i = tid + s * 256;
    int r = i >> 4, c = (i & 15) * 4;      // r=o, c=m
    f32x4 v = *(const f32x4*)&hs[(size_t)r * NNODE + c];
    bf16x4 bv;
    #pragma unroll
    for (int q = 0; q < 4; ++q) bv[q] = (bf16_t)v[q];
    *(bf16x4*)&featT[(size_t)(b * FTR + 64 + r) * NNODE + m0 + c] = bv;
    #pragma unroll
    for (int q = 0; q < 4; ++q) tile[(c + q) * 67 + r] = bv[q];   // tile[m][o]
  }
  __syncthreads();
  #pragma unroll
  for (int s = 0; s < 2; ++s){
    int i = tid + s * 256;                 // r=m(64) x 8-chunks of o
    int r = i >> 3, c = (i & 7) * 8;
    bf16x8 v;
    #pragma unroll
    for (int q = 0; q < 8; ++q) v[q] = tile[r * 67 + c + q];
    *(bf16x8*)&featN[(size_t)(b * NNODE + m0 + r) * NF + 64 + c] = v;
  }
}

// ---------------- graph diffusion: Y^T = X^T * S^T  (tile 64j x 64n) --------------
// plain: t1 = S@xh  -> featT rows 128.. , featN cols 128..
// cheb : t2 = 2*S@t1 - xh -> featN cols 256.. only
__global__ __launch_bounds__(256) void k_smult(bf16_t* featT, const bf16_t* __restrict__ Sb,
                                               bf16_t* featN, int cheb){
  __shared__ union {
    struct { bf16_t A[64 * 40]; bf16_t Bt[64 * 40]; } s;
    bf16_t outT[64 * 66];
  } sm;
  const int n0 = blockIdx.x * 64, jblk = blockIdx.y, b = blockIdx.z;
  const int tid = threadIdx.x, lane = tid & 63, wave = tid >> 6;
  const int wj = wave >> 1, wn = wave & 1;
  const bf16_t* At = featT + (size_t)(b * FTR + (cheb ? 128 : 0) + jblk * 64) * NNODE;
  const bf16_t* Bs = Sb + (size_t)n0 * NNODE;
  f32x4 acc[2][2] = {};
  const int r0 = tid >> 2, sg = (tid & 3) * 8;
  const int ko = (lane >> 4) * 8, fr = lane & 15;
  for (int kt = 0; kt < 16; ++kt){
    const int k0 = kt * 32;
    *(uint4*)&sm.s.A[r0 * 40 + sg]  = *(const uint4*)&At[(size_t)r0 * NNODE + k0 + sg];
    *(uint4*)&sm.s.Bt[r0 * 40 + sg] = *(const uint4*)&Bs[(size_t)r0 * NNODE + k0 + sg];
    __syncthreads();
    bf16x8 bfr[2], afr[2];
    #pragma unroll
    for (int q = 0; q < 2; ++q){
      afr[q] = *(const bf16x8*)&sm.s.A[(wj * 32 + q * 16 + fr) * 40 + ko];
      bfr[q] = *(const bf16x8*)&sm.s.Bt[(wn * 32 + q * 16 + fr) * 40 + ko];
    }
    #pragma unroll
    for (int fj = 0; fj < 2; ++fj)
      #pragma unroll
      for (int fn = 0; fn < 2; ++fn)
        acc[fj][fn] = mfma16(afr[fj], bfr[fn], acc[fj][fn]);
    __syncthreads();
  }
  const int ro = (lane >> 4) * 4;
  if (!cheb){
    #pragma unroll
    for (int fj = 0; fj < 2; ++fj)
      #pragma unroll
      for (int fn = 0; fn < 2; ++fn)
        #pragma unroll
        for (int r = 0; r < 4; ++r){
          int jl = wj * 32 + fj * 16 + ro + r;
          int m  = n0 + wn * 32 + fn * 16 + fr;
          featT[(size_t)(b * FTR + 128 + jblk * 64 + jl) * NNODE + m] = (bf16_t)acc[fj][fn][r];
        }
  }
  // transpose through LDS for the row-major copy (featN)
  #pragma unroll
  for (int fj = 0; fj < 2; ++fj)
    #pragma unroll
    for (int fn = 0; fn < 2; ++fn)
      #pragma unroll
      for (int r = 0; r < 4; ++r){
        int jl = wj * 32 + fj * 16 + ro + r;
        int nl = wn * 32 + fn * 16 + fr;
        float v = acc[fj][fn][r];
        if (cheb) v = 2.0f * v - (float)featT[(size_t)(b * FTR + jblk * 64 + jl) * NNODE + n0 + nl];
        sm.outT[jl * 66 + nl] = (bf16_t)v;
      }
  __syncthreads();
  const int base = (cheb ? 256 : 128) + jblk * 64;
  #pragma unroll
  for (int s = 0; s < 2; ++s){
    int i = tid + s * 256;                 // 512: n(64) x 8 j-chunks
    int n = i >> 3, jc = (i & 7) * 8;
    bf16x8 v;
    #pragma unroll
    for (int q = 0; q < 8; ++q) v[q] = sm.outT[(jc + q) * 66 + n];
    *(bf16x8*)&featN[(size_t)(b * NNODE + n0 + n) * NF + base + jc] = v;
  }
}

// ---------------- gate dense: sigmoid(feat@Wg + bg); write u_t, rh ----------------
__global__ __launch_bounds__(256) void k_gate(bf16_t* featN, const bf16_t* __restrict__ Wgt,
                                              const float* __restrict__ bg,
                                              const float* __restrict__ h_t,
                                              float* __restrict__ u_t, bf16_t* featT){
  __shared__ union {
    struct { bf16_t A[64 * 40]; bf16_t Bt[64 * 40]; } s;
    bf16_t rh[64 * 66];
  } sm;
  const int n0 = blockIdx.x * 64, oblk = blockIdx.y, b = blockIdx.z;
  const int tid = threadIdx.x, lane = tid & 63, wave = tid >> 6;
  const int wn = wave >> 1, wo = wave & 1;
  const bf16_t* An = featN + (size_t)(b * NNODE + n0) * NF;
  f32x4 acc[2][2] = {};
  const int r0 = tid >> 2, sg = (tid & 3) * 8;
  const int ko = (lane >> 4) * 8, fr = lane & 15;
  for (int kt = 0; kt < 12; ++kt){
    const int k0 = kt * 32;
    *(uint4*)&sm.s.A[r0 * 40 + sg]  = *(const uint4*)&An[(size_t)r0 * NF + k0 + sg];
    *(uint4*)&sm.s.Bt[r0 * 40 + sg] = *(const uint4*)&Wgt[(size_t)(oblk * 64 + r0) * NF + k0 + sg];
    __syncthreads();
    bf16x8 afr[2], bfr[2];
    #pragma unroll
    for (int q = 0; q < 2; ++q){
      afr[q] = *(const bf16x8*)&sm.s.A[(wn * 32 + q * 16 + fr) * 40 + ko];
      bfr[q] = *(const bf16x8*)&sm.s.Bt[(wo * 32 + q * 16 + fr) * 40 + ko];
    }
    #pragma unroll
    for (int fn = 0; fn < 2; ++fn)
      #pragma unroll
      for (int fo = 0; fo < 2; ++fo)
        acc[fn][fo] = mfma16(afr[fn], bfr[fo], acc[fn][fo]);
    __syncthreads();
  }
  const int ro = (lane >> 4) * 4;
  #pragma unroll
  for (int fn = 0; fn < 2; ++fn){
    const int nl = wn * 32 + fn * 16 + ro;
    const int n  = n0 + nl;
    #pragma unroll
    for (int fo = 0; fo < 2; ++fo){
      const int ol = wo * 32 + fo * 16 + fr;          // 0..63 within half
      const int o  = oblk * 64 + ol;                  // global gate col
      const float bias = bg[o];
      float g[4];
      #pragma unroll
      for (int r = 0; r < 4; ++r) g[r] = 1.0f / (1.0f + __expf(-(acc[fn][fo][r] + bias)));
      if (oblk == 1){                                  // u gate
        f32x4 uv = { g[0], g[1], g[2], g[3] };
        *(f32x4*)&u_t[(size_t)(b * NH + ol) * NNODE + n] = uv;
      } else {                                         // r gate -> rh
        f32x4 hv = *(const f32x4*)&h_t[(size_t)(b * NH + ol) * NNODE + n];
        bf16x4 rhv;
        #pragma unroll
        for (int r = 0; r < 4; ++r) rhv[r] = (bf16_t)(g[r] * hv[r]);
        *(bf16x4*)&featT[(size_t)(b * FTR + 64 + ol) * NNODE + n] = rhv;
        #pragma unroll
        for (int r = 0; r < 4; ++r) sm.rh[ol * 66 + nl + r] = rhv[r];
      }
    }
  }
  if (oblk == 0){
    __syncthreads();
    #pragma unroll
    for (int s = 0; s < 2; ++s){
      int i = tid + s * 256;               // 512: n(64) x 8 o-chunks
      int n = i >> 3, oc = (i & 7) * 8;
      bf16x8 v;
      #pragma unroll
      for (int q = 0; q < 8; ++q) v[q] = sm.rh[(oc + q) * 66 + n];
      *(bf16x8*)&featN[(size_t)(b * NNODE + n0 + n) * NF + 64 + oc] = v;
    }
  }
}

// ---------------- candidate dense: tanh + GRU update -----------------------------
__global__ __launch_bounds__(256) void k_cand(const bf16_t* __restrict__ featN,
                                              const bf16_t* __restrict__ Wct,
                                              const float* __restrict__ bc,
                                              const float* __restrict__ u_t,
                                              float* __restrict__ h_t,
                                              float* __restrict__ cur){
  __shared__ union {
    struct { bf16_t A[64 * 40]; bf16_t Bt[64 * 40]; } s;
    float nh[64 * 65];
  } sm;
  const int n0 = blockIdx.x * 64, b = blockIdx.y;
  const int tid = threadIdx.x, lane = tid & 63, wave = tid >> 6;
  const int wn = wave >> 1, wo = wave & 1;
  const bf16_t* An = featN + (size_t)(b * NNODE + n0) * NF;
  f32x4 acc[2][2] = {};
  const int r0 = tid >> 2, sg = (tid & 3) * 8;
  const int ko = (lane >> 4) * 8, fr = lane & 15;
  for (int kt = 0; kt < 12; ++kt){
    const int k0 = kt * 32;
    *(uint4*)&sm.s.A[r0 * 40 + sg]  = *(const uint4*)&An[(size_t)r0 * NF + k0 + sg];
    *(uint4*)&sm.s.Bt[r0 * 40 + sg] = *(const uint4*)&Wct[(size_t)r0 * NF + k0 + sg];
    __syncthreads();
    bf16x8 afr[2], bfr[2];
    #pragma unroll
    for (int q = 0; q < 2; ++q){
      afr[q] = *(const bf16x8*)&sm.s.A[(wn * 32 + q * 16 + fr) * 40 + ko];
      bfr[q] = *(const bf16x8*)&sm.s.Bt[(wo * 32 + q * 16 + fr) * 40 + ko];
    }
    #pragma unroll
    for (int fn = 0; fn < 2; ++fn)
      #pragma unroll
      for (int fo = 0; fo < 2; ++fo)
        acc[fn][fo] = mfma16(afr[fn], bfr[fo], acc[fn][fo]);
    __syncthreads();
  }
  const int ro = (lane >> 4) * 4;
  #pragma unroll
  for (int fn = 0; fn < 2; ++fn){
    const int nl = wn * 32 + fn * 16 + ro;
    const int n  = n0 + nl;
    #pragma unroll
    for (int fo = 0; fo < 2; ++fo){
      const int o = wo * 32 + fo * 16 + fr;
      const float bias = bc[o];
      f32x4 uv = *(const f32x4*)&u_t[(size_t)(b * NH + o) * NNODE + n];
      f32x4 hv = *(const f32x4*)&h_t[(size_t)(b * NH + o) * NNODE + n];
      f32x4 nhv;
      #pragma unroll
      for (int r = 0; r < 4; ++r){
        float c = tanhf(acc[fn][fo][r] + bias);
        nhv[r] = uv[r] * hv[r] + (1.0f - uv[r]) * c;
      }
      *(f32x4*)&h_t[(size_t)(b * NH + o) * NNODE + n] = nhv;
      #pragma unroll
      for (int r = 0; r < 4; ++r) sm.nh[o * 65 + nl + r] = nhv[r];
    }
  }
  __syncthreads();
  #pragma unroll
  for (int s = 0; s < 4; ++s){
    int i = tid + s * 256;                 // 1024: n(64) x 16 o-chunks(4)
    int n = i >> 4, oc = (i & 15) * 4;
    f32x4 t;
    #pragma unroll
    for (int q = 0; q < 4; ++q) t[q] = sm.nh[(oc + q) * 65 + n];
    *(f32x4*)&cur[(size_t)(b * NNODE + n0 + n) * NH + oc] = t;
  }
}

// ---------------- host orchestration ---------------------------------------------
extern "C" void kernel_launch(void* const* d_in, const int* in_sizes, int n_in,
                              void* d_out, int out_size, void* d_ws, size_t ws_size,
                              hipStream_t stream){
  const float* inputs = (const float*)d_in[0];
  const float* h0     = (const float*)d_in[1];
  const float* S      = (const float*)d_in[2];
  const float* W_gate = (const float*)d_in[3];
  const float* b_gate = (const float*)d_in[4];
  const float* W_c    = (const float*)d_in[5];
  const float* b_c    = (const float*)d_in[6];
  float* out = (float*)d_out;
  char* ws = (char*)d_ws;

  bf16_t* Sb    = (bf16_t*)(ws + 0);         // 512*512*2          = 524288
  bf16_t* Wgt   = (bf16_t*)(ws + 524288);    // 2*128*384*2        = 196608
  bf16_t* Wct   = (bf16_t*)(ws + 720896);    // 2*64*384*2         = 98304
  bf16_t* featT = (bf16_t*)(ws + 819200);    // 32*256*512*2       = 8388608
  bf16_t* featN = (bf16_t*)(ws + 9207808);   // 32*512*384*2       = 12582912
  float*  h_t   = (float*) (ws + 21790720);  // 32*64*512*4        = 4194304
  float*  u_t   = (float*) (ws + 25985024);  // 4194304 -> end 30179328

  float* finalh = out;                               // [2][B][N*H]
  float* cur    = out + (size_t)2 * NB * NNODE * NH; // [T][B][N*H]

  k_convert_S<<<dim3(256), 256, 0, stream>>>(S, Sb);
  k_transW<<<dim3((2 * NF * 128 + 255) / 256), 256, 0, stream>>>(W_gate, Wgt, 128);
  k_transW<<<dim3((2 * NF * 64 + 255) / 256), 256, 0, stream>>>(W_c, Wct, 64);

  const dim3 blk(256);
  const dim3 gS(8, 2, 32);     // n-tiles x j/o-halves x batch
  const dim3 gC(8, 32);        // n-tiles x batch

  for (int l = 0; l < 2; ++l){
    // h_t = transpose(h0[l]) : per b, (512x64) -> (64x512)
    k_transpose_f32<<<dim3(8, 1, 32), blk, 0, stream>>>(
        h0 + (size_t)l * NB * NNODE * NH, h_t, NH, NNODE,
        (long)NNODE * NH, (long)NH * NNODE);
    for (int t = 0; t < 48; ++t){
      const float* x = (l == 0) ? inputs + (size_t)t * NB * NNODE * NH
                                : cur    + (size_t)t * NB * NNODE * NH;
      k_concat<<<gC, blk, 0, stream>>>(x, h_t, featT, featN);
      k_smult<<<gS, blk, 0, stream>>>(featT, Sb, featN, 0);
      k_smult<<<gS, blk, 0, stream>>>(featT, Sb, featN, 1);
      k_gate<<<gS, blk, 0, stream>>>(featN, Wgt + (size_t)l * 128 * NF,
                                     b_gate + l * 128, h_t, u_t, featT);
      k_smult<<<gS, blk, 0, stream>>>(featT, Sb, featN, 0);
      k_smult<<<gS, blk, 0, stream>>>(featT, Sb, featN, 1);
      k_cand<<<gC, blk, 0, stream>>>(featN, Wct + (size_t)l * 64 * NF,
                                     b_c + l * 64, u_t, h_t,
                                     cur + (size_t)t * NB * NNODE * NH);
    }
    // final hidden for this layer: transpose h_t back to [b][n*64+o]
    k_transpose_f32<<<dim3(1, 8, 32), blk, 0, stream>>>(
        h_t, finalh + (size_t)l * NB * NNODE * NH, NNODE, NH,
        (long)NH * NNODE, (long)NNODE * NH);
  }
}